// Round 8
// baseline (448.565 us; speedup 1.0000x reference)
//
#include <hip/hip_runtime.h>

#define N_NEURONS   100000
#define INPUT_SIZE  1024
#define OUTPUT_SIZE 256
#define E_SYN       10000000
#define STEPS       3

#define RANGES      16             // dst ranges
#define BIN         6250           // neurons per dst range
#define SHIFT       13             // dst_local bits (6250 < 8192)
#define DMASK       8191
#define NSB         16             // src windows; window = 6250 floats = 25KB
#define SBW         6250
#define NCAT        (RANGES * NSB) // 256 (dst-range, src-window) cats
#define CAP         665600         // per-range capacity (mean 625K + ~53 sigma)
#define VEC4        (E_SYN / 4)

// pass-A partition geometry (one wave per chunk, no LDS)
#define CHK         1024
#define NCH         9766               // ceil(E_SYN / CHK)
#define PITER       (CHK / 256)
#define PW          4
#define HIST_GRID   ((NCH + PW - 1) / PW)
#define SCJ         ((NCH + 1023) / 1024)

// pass-B geometry (sub-sort each range bucket by src-window)
#define RCHK        1024               // records per pass-B chunk (8KB tile/wave)
#define JB          (CAP / RCHK)       // 650 chunks per range
#define NCHB        (RANGES * JB)      // 10400
#define HB_GRID     ((NCHB + 3) / 4)
#define SBJ         11                 // scanB items/thread (64*11 >= 650)

// scatter / reduce
#define SC_BLK      1024
#define RG          4                  // reduce: 4 groups of 4 slabs (16 stripes)
#define RSL         (NSB / RG)

// 16-way category select from 4 ballot words
#define CMB(x, b0, b1, b2, b3) \
    ((((x) & 1) ? (b0) : ~(b0)) & (((x) & 2) ? (b1) : ~(b1)) & \
     (((x) & 4) ? (b2) : ~(b2)) & (((x) & 8) ? (b3) : ~(b3)))

// Per-chunk 16-range histogram (ballot counting); v-init fused in.
__global__ __launch_bounds__(256) void hist_kernel(const float* __restrict__ x,
                                                   float* __restrict__ v,
                                                   const int* __restrict__ dst,
                                                   int* __restrict__ hist) {
    const int gidx = blockIdx.x * 256 + threadIdx.x;
    if (gidx < N_NEURONS) v[gidx] = (gidx < INPUT_SIZE) ? x[gidx] : 0.0f;
    const int lane  = threadIdx.x & 63;
    const int wv    = threadIdx.x >> 6;
    const int chunk = blockIdx.x * PW + wv;
    if (chunk >= NCH) return;
    const int beg = chunk * CHK;
    const int4* dst4 = (const int4*)dst;
    int h = 0;
    for (int it = 0; it < PITER; ++it) {
        int e   = beg + (it * 64 + lane) * 4;
        bool ok = (e < E_SYN);
        int4 d4 = ok ? dst4[e >> 2] : make_int4(0, 0, 0, 0);
        unsigned long long okm = __ballot(ok);
        int rk[4] = {d4.x / BIN, d4.y / BIN, d4.z / BIN, d4.w / BIN};
#pragma unroll
        for (int k = 0; k < 4; ++k) {
            unsigned long long b0 = __ballot(rk[k] & 1);
            unsigned long long b1 = __ballot(rk[k] & 2);
            unsigned long long b2 = __ballot(rk[k] & 4);
            unsigned long long b3 = __ballot(rk[k] & 8);
            h += __popcll(CMB(lane, b0, b1, b2, b3) & okm);
        }
    }
    if (lane < RANGES) hist[(size_t)lane * NCH + chunk] = h;
}

// Per-range exclusive scan over chunk counts -> dense bases + totals.
__global__ __launch_bounds__(1024) void scan_kernel(const int* __restrict__ hist,
                                                    int* __restrict__ bases,
                                                    int* __restrict__ gcur) {
    const int r = blockIdx.x;
    const int t = threadIdx.x;
    const int lane = t & 63;
    const int wv   = t >> 6;
    int vals[SCJ];
    int s = 0;
#pragma unroll
    for (int j = 0; j < SCJ; ++j) {
        int idx = t * SCJ + j;
        int vv  = (idx < NCH) ? hist[(size_t)r * NCH + idx] : 0;
        vals[j] = vv;
        s += vv;
    }
    int x = s;
#pragma unroll
    for (int d = 1; d < 64; d <<= 1) {
        int y = __shfl_up(x, d, 64);
        if (lane >= d) x += y;
    }
    __shared__ int wsum[16];
    if (lane == 63) wsum[wv] = x;
    __syncthreads();
    if (wv == 0) {
        int y = (lane < 16) ? wsum[lane] : 0;
        int z = y;
#pragma unroll
        for (int d = 1; d < 16; d <<= 1) {
            int u = __shfl_up(z, d, 64);
            if (lane >= d) z += u;
        }
        if (lane < 16) wsum[lane] = z - y;
    }
    __syncthreads();
    int run = (x - s) + wsum[wv];
#pragma unroll
    for (int j = 0; j < SCJ; ++j) {
        int idx = t * SCJ + j;
        if (idx < NCH) bases[(size_t)r * NCH + idx] = r * CAP + run;
        run += vals[j];
    }
    if (t == 1023) gcur[r] = run;
}

// Pass A: partition into 16 range-major buckets (ballot-rank direct scatter).
__global__ __launch_bounds__(256) void partition_kernel(
        const float* __restrict__ w,
        const int*   __restrict__ src,
        const int*   __restrict__ dst,
        const int*   __restrict__ bases,
        int2* __restrict__ recs) {
    const int lane  = threadIdx.x & 63;
    const int wv    = threadIdx.x >> 6;
    const int chunk = blockIdx.x * PW + wv;
    if (chunk >= NCH) return;
    const unsigned long long ltmask = (1ull << lane) - 1ull;

    int cur = 0;                              // lane r<16 holds range r's cursor
    if (lane < RANGES) cur = bases[(size_t)lane * NCH + chunk];

    const int beg = chunk * CHK;
    const int4* dst4 = (const int4*)dst;
    const int4* src4 = (const int4*)src;
    const int4* wq4  = (const int4*)w;

    for (int it = 0; it < PITER; ++it) {
        int e   = beg + (it * 64 + lane) * 4;
        bool ok = (e < E_SYN);
        int idx = e >> 2;
        int4 d4 = ok ? dst4[idx] : make_int4(0, 0, 0, 0);
        int4 s4 = ok ? src4[idx] : make_int4(0, 0, 0, 0);
        int4 q4 = ok ? wq4[idx]  : make_int4(0, 0, 0, 0);
        unsigned long long okm = __ballot(ok);
        int dd[4] = {d4.x, d4.y, d4.z, d4.w};
        int ss[4] = {s4.x, s4.y, s4.z, s4.w};
        int qq[4] = {q4.x, q4.y, q4.z, q4.w};
#pragma unroll
        for (int k = 0; k < 4; ++k) {
            int d = dd[k];
            int r = d / BIN;
            unsigned long long b0 = __ballot(r & 1);
            unsigned long long b1 = __ballot(r & 2);
            unsigned long long b2 = __ballot(r & 4);
            unsigned long long b3 = __ballot(r & 8);
            unsigned long long mym = CMB(r, b0, b1, b2, b3) & okm;
            int rank = __popcll(mym & ltmask);
            int gpos = __shfl(cur, r, 64) + rank;
            if (ok) recs[(size_t)gpos] =
                make_int2((ss[k] << SHIFT) | (d - r * BIN), qq[k]);
            unsigned long long mm = CMB(lane, b0, b1, b2, b3) & okm;
            cur += __popcll(mm);
        }
    }
}

// Pass B1: per-chunk 16-window histogram within each range bucket.
__global__ __launch_bounds__(256) void histB_kernel(const int2* __restrict__ recs,
                                                    const int*  __restrict__ gcur,
                                                    int* __restrict__ histB) {
    const int lane = threadIdx.x & 63;
    const int wv   = threadIdx.x >> 6;
    const int gid  = blockIdx.x * 4 + wv;
    if (gid >= NCHB) return;
    const int r = gid / JB;
    const int j = gid - r * JB;
    const int cnt = gcur[r];
    int h = 0;
    const int c = lane & 15;
    if (j * RCHK < cnt) {
        const int2* rb = recs + (size_t)r * CAP + (size_t)j * RCHK;
        int lim = cnt - j * RCHK;
        if (lim > RCHK) lim = RCHK;
        for (int it = 0; it < RCHK / 64; ++it) {
            int idx = it * 64 + lane;
            bool ok = idx < lim;
            int rx  = ok ? rb[idx].x : 0;
            int sb  = (rx >> SHIFT) / SBW;
            unsigned long long okm = __ballot(ok);
            unsigned long long b0 = __ballot(sb & 1);
            unsigned long long b1 = __ballot(sb & 2);
            unsigned long long b2 = __ballot(sb & 4);
            unsigned long long b3 = __ballot(sb & 8);
            h += __popcll(CMB(c, b0, b1, b2, b3) & okm);
        }
    }
    if (lane < NSB) histB[(size_t)(r * NSB + lane) * JB + j] = h;
}

// Pass B2: per-cat exclusive scan over 650 chunk counts (one wave per cat).
__global__ __launch_bounds__(64) void scanB_kernel(const int* __restrict__ histB,
                                                   int* __restrict__ basesB,
                                                   int* __restrict__ totB) {
    const int cat  = blockIdx.x;
    const int lane = threadIdx.x;
    int vals[SBJ];
    int s = 0;
#pragma unroll
    for (int j = 0; j < SBJ; ++j) {
        int idx = lane * SBJ + j;
        int vv  = (idx < JB) ? histB[(size_t)cat * JB + idx] : 0;
        vals[j] = vv;
        s += vv;
    }
    int x = s;
#pragma unroll
    for (int d = 1; d < 64; d <<= 1) {
        int y = __shfl_up(x, d, 64);
        if (lane >= d) x += y;
    }
    int run = x - s;
#pragma unroll
    for (int j = 0; j < SBJ; ++j) {
        int idx = lane * SBJ + j;
        if (idx < JB) basesB[(size_t)cat * JB + idx] = run;
        run += vals[j];
    }
    if (lane == 63) totB[cat] = x;
}

// Pass B3: absolute cat starts (even-aligned for int4 pair streaming);
// zero-weight dummy record fills each odd-length cat's pad slot.
__global__ void composeB_kernel(const int* __restrict__ totB,
                                int* __restrict__ catStart,
                                int2* __restrict__ recs2) {
    __shared__ int cs[NCAT];
    const int t = threadIdx.x;   // 256
    if (t < RANGES) {
        int s = t * CAP;
        for (int sb = 0; sb < NSB; ++sb) {
            int c = t * NSB + sb;
            cs[c] = s;
            s = (s + totB[c] + 1) & ~1;
        }
    }
    __syncthreads();
    if (t < NCAT) {
        catStart[t] = cs[t];
        int tot = totB[t];
        if (tot & 1) {
            int sb = t & (NSB - 1);
            recs2[(size_t)cs[t] + tot] = make_int2((sb * SBW) << SHIFT, 0);
        }
    }
}

// Pass B4: local counting-sort per 1024-record chunk (one wave, 8KB tile),
// then burst each window segment as long coalesced runs (~64 recs = 512B;
// consecutive chunks concatenate globally -> full-line writes).
__global__ __launch_bounds__(256) void partB_kernel(const int2* __restrict__ recs,
                                                    const int*  __restrict__ gcur,
                                                    const int*  __restrict__ histB,
                                                    const int*  __restrict__ basesB,
                                                    const int*  __restrict__ catStart,
                                                    int2* __restrict__ recs2) {
    __shared__ int2 tile[4][RCHK];
    const int lane = threadIdx.x & 63;
    const int wv   = threadIdx.x >> 6;
    const int gid  = blockIdx.x * 4 + wv;
    if (gid >= NCHB) return;
    const int r = gid / JB;
    const int j = gid - r * JB;
    const int cnt = gcur[r];
    if (j * RCHK >= cnt) return;
    const unsigned long long ltmask = (1ull << lane) - 1ull;

    int h = 0, gd = 0;
    if (lane < NSB) {
        h  = histB[(size_t)(r * NSB + lane) * JB + j];
        gd = catStart[r * NSB + lane] + basesB[(size_t)(r * NSB + lane) * JB + j];
    }
    int x = h;
#pragma unroll
    for (int d = 1; d < 16; d <<= 1) {
        int y = __shfl_up(x, d, 64);
        if (lane >= d) x += y;
    }
    const int lb = x - h;

    int2* tl = tile[wv];
    const int4* rb4 = (const int4*)(recs + (size_t)r * CAP + (size_t)j * RCHK);
    int lim = cnt - j * RCHK;
    if (lim > RCHK) lim = RCHK;
    int cnt_c = 0;                       // lane c<16 owns window c's running count
    for (int it = 0; it < RCHK / 128; ++it) {
        int pi = it * 64 + lane;
        int4 p = rb4[pi];                // within CAP allocation always
#pragma unroll
        for (int k = 0; k < 2; ++k) {
            bool ok = (pi * 2 + k) < lim;
            int rx = ok ? (k ? p.z : p.x) : 0;
            int ry = k ? p.w : p.y;
            int sb = (rx >> SHIFT) / SBW;
            unsigned long long okm = __ballot(ok);
            unsigned long long b0 = __ballot(sb & 1);
            unsigned long long b1 = __ballot(sb & 2);
            unsigned long long b2 = __ballot(sb & 4);
            unsigned long long b3 = __ballot(sb & 8);
            unsigned long long mym = CMB(sb, b0, b1, b2, b3) & okm;
            int rank = __popcll(mym & ltmask);
            int pos  = __shfl(lb + cnt_c, sb, 64) + rank;
            if (ok) tl[pos] = make_int2(rx, ry);
            unsigned long long mm = CMB(lane, b0, b1, b2, b3) & okm;
            cnt_c += __popcll(mm);
        }
    }
    for (int c = 0; c < NSB; ++c) {
        const int len = __shfl(cnt_c, c, 64);
        const int lbc = __shfl(lb, c, 64);
        const int gdc = __shfl(gd, c, 64);
        for (int off = lane; off < len; off += 64)
            recs2[(size_t)gdc + off] = tl[lbc + off];
    }
}

// Per step: persistent cat blocks. Block (r,sb) stages its 25KB v-window ONCE,
// streams its whole cat contiguously; gather AND accumulate are LDS ops.
// Grid = 256 = 1 block/CU; staging traffic 6.4MB total (vs 200MB round-5).
__global__ __launch_bounds__(SC_BLK) void scatter_cat(
        const int2* __restrict__ recs2,
        const int*  __restrict__ catStart,
        const int*  __restrict__ totB,
        const float* __restrict__ v,
        float* __restrict__ partials) {
    __shared__ float bins[BIN];
    __shared__ float vst[SBW];
    const int r   = blockIdx.x >> 4;
    const int sb  = blockIdx.x & 15;
    const int tid = threadIdx.x;
    for (int j = tid; j < BIN; j += SC_BLK) bins[j] = 0.0f;
    const float2* vs2 = (const float2*)(v + sb * SBW);
    float2* vt2 = (float2*)vst;
    for (int j = tid; j < SBW / 2; j += SC_BLK) vt2[j] = vs2[j];
    __syncthreads();

    const int cat   = r * NSB + sb;
    const int start = catStart[cat];
    const int P     = (totB[cat] + 1) >> 1;   // padded pair count
    const int4* c4  = (const int4*)(recs2 + (size_t)start);
    const int sbb   = sb * SBW;
    int u = tid;
    for (; u + 7 * SC_BLK < P; u += 8 * SC_BLK) {
        int4 A[8];
#pragma unroll
        for (int i = 0; i < 8; ++i) A[i] = c4[u + i * SC_BLK];
        float g[16];
#pragma unroll
        for (int i = 0; i < 8; ++i) {
            g[2 * i]     = vst[(A[i].x >> SHIFT) - sbb];
            g[2 * i + 1] = vst[(A[i].z >> SHIFT) - sbb];
        }
#pragma unroll
        for (int i = 0; i < 8; ++i) {
            atomicAdd(&bins[A[i].x & DMASK], g[2 * i]     * __int_as_float(A[i].y));
            atomicAdd(&bins[A[i].z & DMASK], g[2 * i + 1] * __int_as_float(A[i].w));
        }
    }
    for (; u < P; u += SC_BLK) {
        int4 a = c4[u];
        float v0 = vst[(a.x >> SHIFT) - sbb];
        float v1 = vst[(a.z >> SHIFT) - sbb];
        atomicAdd(&bins[a.x & DMASK], v0 * __int_as_float(a.y));
        atomicAdd(&bins[a.z & DMASK], v1 * __int_as_float(a.w));
    }
    __syncthreads();
    float* o = partials + (size_t)sb * N_NEURONS + r * BIN;
    for (int j = tid; j < BIN; j += SC_BLK) o[j] = bins[j];
}

// Fused reduce over [stripe][global] partials: 16 stripes as 4 groups of 4,
// then bias + tanh (except outputs). Aligned float4, no straddling.
__global__ void reduce_fused(const float* __restrict__ partials,
                             const float* __restrict__ bias,
                             float* __restrict__ v,
                             float* __restrict__ out,
                             int write_out) {
    int i4 = 4 * (blockIdx.x * blockDim.x + threadIdx.x);
    if (i4 >= N_NEURONS) return;
    const float* base = partials + i4;
    float4 tot = {0.f, 0.f, 0.f, 0.f};
#pragma unroll
    for (int g = 0; g < RG; ++g) {
        float4 a = {0.f, 0.f, 0.f, 0.f};
#pragma unroll
        for (int cc = 0; cc < RSL; ++cc) {
            float4 p = *(const float4*)(base + (size_t)(g * RSL + cc) * N_NEURONS);
            a.x += p.x; a.y += p.y; a.z += p.z; a.w += p.w;
        }
        tot.x += a.x; tot.y += a.y; tot.z += a.z; tot.w += a.w;
    }
    float av[4] = {tot.x, tot.y, tot.z, tot.w};
#pragma unroll
    for (int k = 0; k < 4; ++k) {
        int i = i4 + k;
        float val = av[k] + ((i >= INPUT_SIZE) ? bias[i - INPUT_SIZE] : 0.0f);
        float nv  = (i < N_NEURONS - OUTPUT_SIZE) ? tanhf(val) : val;
        v[i] = nv;
        if (write_out && i >= N_NEURONS - OUTPUT_SIZE)
            out[i - (N_NEURONS - OUTPUT_SIZE)] = val;
    }
}

// ---- fallback (small ws): multi-pass binned rescan path ----
__global__ void init_state_fb(const float* __restrict__ x, float* __restrict__ v) {
    int i = blockIdx.x * blockDim.x + threadIdx.x;
    if (i < N_NEURONS) v[i] = (i < INPUT_SIZE) ? x[i] : 0.0f;
}
__global__ void scatter_binned(const float* __restrict__ w,
                               const int*   __restrict__ src,
                               const int*   __restrict__ dst,
                               const float* __restrict__ v,
                               float*       __restrict__ partials,
                               int C) {
    __shared__ float bins[BIN];
    const int r = blockIdx.x / C;
    const int c = blockIdx.x % C;
    const int lo = r * BIN;
    const int hi = lo + BIN;
    for (int j = threadIdx.x; j < BIN; j += blockDim.x) bins[j] = 0.0f;
    __syncthreads();
    const int4*   src4 = (const int4*)src;
    const int4*   dst4 = (const int4*)dst;
    const float4* w4v  = (const float4*)w;
    const int stride = C * blockDim.x;
    for (int u = c * blockDim.x + threadIdx.x; u < VEC4; u += stride) {
        const int4   s4 = src4[u];
        const int4   d4 = dst4[u];
        const float4 wv = w4v[u];
        int   s[4] = {s4.x, s4.y, s4.z, s4.w};
        int   d[4] = {d4.x, d4.y, d4.z, d4.w};
        float ww[4] = {wv.x, wv.y, wv.z, wv.w};
#pragma unroll
        for (int k = 0; k < 4; ++k)
            if (d[k] >= lo && d[k] < hi)
                atomicAdd(&bins[d[k] - lo], v[s[k]] * ww[k]);
    }
    __syncthreads();
    float* o = partials + (size_t)c * N_NEURONS + r * BIN;
    for (int j = threadIdx.x; j < BIN; j += blockDim.x) o[j] = bins[j];
}
__global__ void reduce_update_fb(const float* __restrict__ partials,
                                 const float* __restrict__ bias,
                                 float* __restrict__ v,
                                 float* __restrict__ out,
                                 int C, int write_out) {
    int i4 = 4 * (blockIdx.x * blockDim.x + threadIdx.x);
    if (i4 >= N_NEURONS) return;
    const float* base = partials + i4;
    float4 acc = {0.f, 0.f, 0.f, 0.f};
    for (int c = 0; c < C; ++c) {
        float4 p = *(const float4*)(base + (size_t)c * N_NEURONS);
        acc.x += p.x; acc.y += p.y; acc.z += p.z; acc.w += p.w;
    }
    float av[4] = {acc.x, acc.y, acc.z, acc.w};
#pragma unroll
    for (int k = 0; k < 4; ++k) {
        int i = i4 + k;
        float val = av[k] + ((i >= INPUT_SIZE) ? bias[i - INPUT_SIZE] : 0.0f);
        float nv  = (i < N_NEURONS - OUTPUT_SIZE) ? tanhf(val) : val;
        v[i] = nv;
        if (write_out && i >= N_NEURONS - OUTPUT_SIZE)
            out[i - (N_NEURONS - OUTPUT_SIZE)] = val;
    }
}

extern "C" void kernel_launch(void* const* d_in, const int* in_sizes, int n_in,
                              void* d_out, int out_size, void* d_ws, size_t ws_size,
                              hipStream_t stream) {
    const float* x    = (const float*)d_in[0];
    const float* w    = (const float*)d_in[1];
    const float* bias = (const float*)d_in[2];
    const int*   src  = (const int*)d_in[3];
    const int*   dst  = (const int*)d_in[4];
    float* out = (float*)d_out;

    const int blk = 256;
    const int grid_n   = (N_NEURONS + blk - 1) / blk;
    const int red_grid = (N_NEURONS / 4 + blk - 1) / blk;

    // ws layout: v | partials(16N) | histA | basesA | histB | basesB |
    //            totB | catStart | gcur | recs | recs2
    float* v        = (float*)d_ws;
    float* partials = v + N_NEURONS;
    int*   histA    = (int*)(partials + (size_t)NSB * N_NEURONS);
    int*   basesA   = histA + (size_t)RANGES * NCH;
    int*   histB    = basesA + (size_t)RANGES * NCH;
    int*   basesB   = histB + (size_t)NCAT * JB;
    int*   totB     = basesB + (size_t)NCAT * JB;
    int*   catStart = totB + NCAT;
    int*   gcur     = catStart + NCAT;
    int2*  recs     = (int2*)(gcur + RANGES);
    int2*  recs2    = recs + (size_t)RANGES * CAP;
    size_t need = (size_t)((char*)(recs2 + (size_t)RANGES * CAP) - (char*)d_ws);

    if (ws_size >= need) {
        hist_kernel<<<HIST_GRID, 256, 0, stream>>>(x, v, dst, histA);
        scan_kernel<<<RANGES, 1024, 0, stream>>>(histA, basesA, gcur);
        partition_kernel<<<HIST_GRID, 256, 0, stream>>>(w, src, dst, basesA, recs);
        histB_kernel<<<HB_GRID, 256, 0, stream>>>(recs, gcur, histB);
        scanB_kernel<<<NCAT, 64, 0, stream>>>(histB, basesB, totB);
        composeB_kernel<<<1, 256, 0, stream>>>(totB, catStart, recs2);
        partB_kernel<<<HB_GRID, 256, 0, stream>>>(recs, gcur, histB, basesB,
                                                  catStart, recs2);
        for (int s = 0; s < STEPS; ++s) {
            scatter_cat<<<NCAT, SC_BLK, 0, stream>>>(
                recs2, catStart, totB, v, partials);
            reduce_fused<<<red_grid, blk, 0, stream>>>(
                partials, bias, v, out, s == STEPS - 1 ? 1 : 0);
        }
    } else {
        long C = (long)(ws_size / 4 / N_NEURONS) - 1;
        if (C > 16) C = 16;
        if (C < 1) C = 1;
        float* part_fb = v + N_NEURONS;
        init_state_fb<<<grid_n, blk, 0, stream>>>(x, v);
        for (int s = 0; s < STEPS; ++s) {
            scatter_binned<<<RANGES * (int)C, SC_BLK, 0, stream>>>(
                w, src, dst, v, part_fb, (int)C);
            reduce_update_fb<<<red_grid, blk, 0, stream>>>(
                part_fb, bias, v, out, (int)C, s == STEPS - 1 ? 1 : 0);
        }
    }
}

// Round 9
// 388.061 us; speedup vs baseline: 1.1559x; 1.1559x over previous
//
#include <hip/hip_runtime.h>

#define N_NEURONS   100000
#define INPUT_SIZE  1024
#define OUTPUT_SIZE 256
#define E_SYN       10000000
#define STEPS       3

#define RANGES      8
#define BIN         12500          // neurons per range; RANGES*BIN == N_NEURONS
#define SCAT_BLK    1024           // 2 blocks/CU -> 32 waves/CU
#define CBLK        64             // blocks per range in scatter
#define RG          8              // reduce groups
#define RSL         (CBLK / RG)    // 8 slabs per group
#define CAP         1280000        // per-range bucket capacity (~28 sigma margin)
#define VEC4        (E_SYN / 4)

// partition geometry (one wave per chunk, no LDS). CHK=512 doubles wave count
// vs round-2 (grid 4883 blocks -> ~76 waves/CU offered) to fix the measured
// 58% occupancy on the latency-bound partition kernel.
#define CHK         512
#define NCH         19532                // ceil(E_SYN / CHK)
#define PITER       (CHK / 256)          // 2 int4 iterations per wave
#define PW          4                    // waves (chunks) per 256-thr block
#define HIST_GRID   ((NCH + PW - 1) / PW)
#define SCJ         ((NCH + 1023) / 1024)   // scan items per thread (20)

// Per-chunk 8-range histogram (ballot counting); v-init fused in.
__global__ __launch_bounds__(256) void hist_kernel(const float* __restrict__ x,
                                                   float* __restrict__ v,
                                                   const int* __restrict__ dst,
                                                   int* __restrict__ hist) {
    const int gidx = blockIdx.x * 256 + threadIdx.x;
    if (gidx < N_NEURONS) v[gidx] = (gidx < INPUT_SIZE) ? x[gidx] : 0.0f;
    const int lane  = threadIdx.x & 63;
    const int wv    = threadIdx.x >> 6;
    const int chunk = blockIdx.x * PW + wv;
    if (chunk >= NCH) return;
    const int beg = chunk * CHK;
    const int4* dst4 = (const int4*)dst;
    int h = 0;
    for (int it = 0; it < PITER; ++it) {
        int e   = beg + (it * 64 + lane) * 4;
        bool ok = (e < E_SYN);
        int4 d4 = ok ? dst4[e >> 2] : make_int4(0, 0, 0, 0);
        unsigned long long okm = __ballot(ok);
        int rk[4] = {d4.x / BIN, d4.y / BIN, d4.z / BIN, d4.w / BIN};
#pragma unroll
        for (int k = 0; k < 4; ++k) {
            unsigned long long b0 = __ballot(rk[k] & 1);
            unsigned long long b1 = __ballot(rk[k] & 2);
            unsigned long long b2 = __ballot(rk[k] & 4);
            unsigned long long m = ((lane & 1) ? b0 : ~b0) &
                                   ((lane & 2) ? b1 : ~b1) &
                                   ((lane & 4) ? b2 : ~b2) & okm;
            h += __popcll(m);
        }
    }
    if (lane < RANGES) hist[(size_t)lane * NCH + chunk] = h;
}

// Per-range exclusive scan over chunk counts -> dense bases + totals.
__global__ __launch_bounds__(1024) void scan_kernel(const int* __restrict__ hist,
                                                    int* __restrict__ bases,
                                                    int* __restrict__ gcur) {
    const int r = blockIdx.x;
    const int t = threadIdx.x;
    const int lane = t & 63;
    const int wv   = t >> 6;
    int vals[SCJ];
    int s = 0;
#pragma unroll
    for (int j = 0; j < SCJ; ++j) {
        int idx = t * SCJ + j;
        int vv  = (idx < NCH) ? hist[(size_t)r * NCH + idx] : 0;
        vals[j] = vv;
        s += vv;
    }
    int x = s;
#pragma unroll
    for (int d = 1; d < 64; d <<= 1) {
        int y = __shfl_up(x, d, 64);
        if (lane >= d) x += y;
    }
    __shared__ int wsum[16];
    if (lane == 63) wsum[wv] = x;
    __syncthreads();
    if (wv == 0) {
        int y = (lane < 16) ? wsum[lane] : 0;
        int z = y;
#pragma unroll
        for (int d = 1; d < 16; d <<= 1) {
            int u = __shfl_up(z, d, 64);
            if (lane >= d) z += u;
        }
        if (lane < 16) wsum[lane] = z - y;
    }
    __syncthreads();
    int run = (x - s) + wsum[wv];
#pragma unroll
    for (int j = 0; j < SCJ; ++j) {
        int idx = t * SCJ + j;
        if (idx < NCH) bases[(size_t)r * NCH + idx] = r * CAP + run;
        run += vals[j];
    }
    if (t == 1023) gcur[r] = run;
}

// Partition into 8 range-major buckets of packed 8B records (ballot-rank
// direct scatter; lane r<8 owns range r's cursor). Round-2-verbatim logic.
__global__ __launch_bounds__(256) void partition_kernel(
        const float* __restrict__ w,
        const int*   __restrict__ src,
        const int*   __restrict__ dst,
        const int*   __restrict__ bases,
        int2* __restrict__ recs) {
    const int lane  = threadIdx.x & 63;
    const int wv    = threadIdx.x >> 6;
    const int chunk = blockIdx.x * PW + wv;
    if (chunk >= NCH) return;
    const unsigned long long ltmask = (1ull << lane) - 1ull;

    int cur = 0;                              // lane r holds range r's cursor
    if (lane < RANGES) cur = bases[(size_t)lane * NCH + chunk];

    const int beg = chunk * CHK;
    const int4* dst4 = (const int4*)dst;
    const int4* src4 = (const int4*)src;
    const int4* wq4  = (const int4*)w;

    for (int it = 0; it < PITER; ++it) {
        int e   = beg + (it * 64 + lane) * 4;
        bool ok = (e < E_SYN);
        int idx = e >> 2;
        int4 d4 = ok ? dst4[idx] : make_int4(0, 0, 0, 0);
        int4 s4 = ok ? src4[idx] : make_int4(0, 0, 0, 0);
        int4 q4 = ok ? wq4[idx]  : make_int4(0, 0, 0, 0);
        unsigned long long okm = __ballot(ok);
        int dd[4] = {d4.x, d4.y, d4.z, d4.w};
        int ss[4] = {s4.x, s4.y, s4.z, s4.w};
        int qq[4] = {q4.x, q4.y, q4.z, q4.w};
#pragma unroll
        for (int k = 0; k < 4; ++k) {
            int d = dd[k];
            int r = d / BIN;
            unsigned long long b0 = __ballot(r & 1);
            unsigned long long b1 = __ballot(r & 2);
            unsigned long long b2 = __ballot(r & 4);
            unsigned long long mym = ((r & 1) ? b0 : ~b0) &
                                     ((r & 2) ? b1 : ~b1) &
                                     ((r & 4) ? b2 : ~b2) & okm;
            int rank = __popcll(mym & ltmask);
            int gpos = __shfl(cur, r, 64) + rank;
            if (ok) recs[(size_t)gpos] =
                make_int2((ss[k] << 14) | (d - r * BIN), qq[k]);
            unsigned long long mm = ((lane & 1) ? b0 : ~b0) &
                                    ((lane & 2) ? b1 : ~b1) &
                                    ((lane & 4) ? b2 : ~b2) & okm;
            cur += __popcll(mm);
        }
    }
}

// Per step: block (r,c) streams a stripe of bucket r (2 packed edges per int4,
// 4x unrolled), LDS-bins, flushes partial slab. Round-2 verbatim (measured
// best scatter config: 62.2 us).
__global__ __launch_bounds__(SCAT_BLK) void scatter_sorted(
        const int2* __restrict__ recs,
        const int*  __restrict__ gcur,
        const float* __restrict__ v,
        float* __restrict__ partials) {
    __shared__ float bins[BIN];
    const int r = blockIdx.x / CBLK;
    const int c = blockIdx.x % CBLK;
    for (int j = threadIdx.x; j < BIN; j += SCAT_BLK) bins[j] = 0.0f;
    __syncthreads();

    const int cnt   = gcur[r];
    const int npair = cnt >> 1;
    const int4* base4 = (const int4*)(recs + (size_t)r * CAP);
    const int stride = CBLK * SCAT_BLK;
    int u = c * SCAT_BLK + threadIdx.x;
    for (; u + 3 * stride < npair; u += 4 * stride) {
        int4 a = base4[u];
        int4 b = base4[u + stride];
        int4 e = base4[u + 2 * stride];
        int4 f = base4[u + 3 * stride];
        float va0 = v[a.x >> 14];
        float va1 = v[a.z >> 14];
        float vb0 = v[b.x >> 14];
        float vb1 = v[b.z >> 14];
        float ve0 = v[e.x >> 14];
        float ve1 = v[e.z >> 14];
        float vf0 = v[f.x >> 14];
        float vf1 = v[f.z >> 14];
        atomicAdd(&bins[a.x & 16383], va0 * __int_as_float(a.y));
        atomicAdd(&bins[a.z & 16383], va1 * __int_as_float(a.w));
        atomicAdd(&bins[b.x & 16383], vb0 * __int_as_float(b.y));
        atomicAdd(&bins[b.z & 16383], vb1 * __int_as_float(b.w));
        atomicAdd(&bins[e.x & 16383], ve0 * __int_as_float(e.y));
        atomicAdd(&bins[e.z & 16383], ve1 * __int_as_float(e.w));
        atomicAdd(&bins[f.x & 16383], vf0 * __int_as_float(f.y));
        atomicAdd(&bins[f.z & 16383], vf1 * __int_as_float(f.w));
    }
    for (; u < npair; u += stride) {
        int4 a = base4[u];
        atomicAdd(&bins[a.x & 16383], v[a.x >> 14] * __int_as_float(a.y));
        atomicAdd(&bins[a.z & 16383], v[a.z >> 14] * __int_as_float(a.w));
    }
    if ((cnt & 1) && c == 0 && threadIdx.x == 0) {
        int2 p = recs[(size_t)r * CAP + cnt - 1];
        atomicAdd(&bins[p.x & 16383], v[p.x >> 14] * __int_as_float(p.y));
    }
    __syncthreads();
    float* o = partials + (size_t)(r * CBLK + c) * BIN;
    for (int j = threadIdx.x; j < BIN; j += SCAT_BLK) o[j] = bins[j];
}

// Reduce stage 1: group g sums its 8 slabs -> p2[g][N]. Grid dim3(98, 8)
// restores full parallelism (784 blocks) vs the under-parallel fused reduce.
__global__ void reduce_stage1(const float* __restrict__ partials,
                              float* __restrict__ p2) {
    int i4 = 4 * (blockIdx.x * blockDim.x + threadIdx.x);
    if (i4 >= N_NEURONS) return;
    const int g = blockIdx.y;
    const int r = i4 / BIN;
    const int j = i4 - r * BIN;
    const float* base = partials + ((size_t)(r * CBLK + g * RSL)) * BIN + j;
    float4 acc = {0.f, 0.f, 0.f, 0.f};
#pragma unroll
    for (int c = 0; c < RSL; ++c) {
        float4 p = *(const float4*)(base + (size_t)c * BIN);
        acc.x += p.x; acc.y += p.y; acc.z += p.z; acc.w += p.w;
    }
    *(float4*)(p2 + (size_t)g * N_NEURONS + i4) = acc;
}

// Reduce stage 2: sum RG group-partials, add bias, tanh (except outputs).
// Association identical to rounds 0-2 (8 sequential groups of 8).
__global__ void reduce_stage2(const float* __restrict__ p2,
                              const float* __restrict__ bias,
                              float* __restrict__ v,
                              float* __restrict__ out,
                              int write_out) {
    int i4 = 4 * (blockIdx.x * blockDim.x + threadIdx.x);
    if (i4 >= N_NEURONS) return;
    float4 acc = {0.f, 0.f, 0.f, 0.f};
#pragma unroll
    for (int g = 0; g < RG; ++g) {
        float4 p = *(const float4*)(p2 + (size_t)g * N_NEURONS + i4);
        acc.x += p.x; acc.y += p.y; acc.z += p.z; acc.w += p.w;
    }
    float av[4] = {acc.x, acc.y, acc.z, acc.w};
#pragma unroll
    for (int k = 0; k < 4; ++k) {
        int i = i4 + k;
        float val = av[k] + ((i >= INPUT_SIZE) ? bias[i - INPUT_SIZE] : 0.0f);
        float nv  = (i < N_NEURONS - OUTPUT_SIZE) ? tanhf(val) : val;
        v[i] = nv;
        if (write_out && i >= N_NEURONS - OUTPUT_SIZE)
            out[i - (N_NEURONS - OUTPUT_SIZE)] = val;
    }
}

// ---- fallback (small ws): multi-pass binned rescan path ----
__global__ void init_state_fb(const float* __restrict__ x, float* __restrict__ v) {
    int i = blockIdx.x * blockDim.x + threadIdx.x;
    if (i < N_NEURONS) v[i] = (i < INPUT_SIZE) ? x[i] : 0.0f;
}
__global__ void scatter_binned(const float* __restrict__ w,
                               const int*   __restrict__ src,
                               const int*   __restrict__ dst,
                               const float* __restrict__ v,
                               float*       __restrict__ partials,
                               int C) {
    __shared__ float bins[BIN];
    const int r = blockIdx.x / C;
    const int c = blockIdx.x % C;
    const int lo = r * BIN;
    const int hi = lo + BIN;
    for (int j = threadIdx.x; j < BIN; j += blockDim.x) bins[j] = 0.0f;
    __syncthreads();
    const int4*   src4 = (const int4*)src;
    const int4*   dst4 = (const int4*)dst;
    const float4* w4v  = (const float4*)w;
    const int stride = C * blockDim.x;
    for (int u = c * blockDim.x + threadIdx.x; u < VEC4; u += stride) {
        const int4   s4 = src4[u];
        const int4   d4 = dst4[u];
        const float4 wv = w4v[u];
        int   s[4] = {s4.x, s4.y, s4.z, s4.w};
        int   d[4] = {d4.x, d4.y, d4.z, d4.w};
        float ww[4] = {wv.x, wv.y, wv.z, wv.w};
#pragma unroll
        for (int k = 0; k < 4; ++k)
            if (d[k] >= lo && d[k] < hi)
                atomicAdd(&bins[d[k] - lo], v[s[k]] * ww[k]);
    }
    __syncthreads();
    float* o = partials + ((size_t)(r * C + c)) * BIN;
    for (int j = threadIdx.x; j < BIN; j += blockDim.x) o[j] = bins[j];
}
__global__ void reduce_update_fb(const float* __restrict__ partials,
                                 const float* __restrict__ bias,
                                 float* __restrict__ v,
                                 float* __restrict__ out,
                                 int C, int write_out) {
    int i4 = 4 * (blockIdx.x * blockDim.x + threadIdx.x);
    if (i4 >= N_NEURONS) return;
    const int r = i4 / BIN;
    const int j = i4 - r * BIN;
    const float* base = partials + ((size_t)r * C) * BIN + j;
    float4 acc = {0.f, 0.f, 0.f, 0.f};
    for (int c = 0; c < C; ++c) {
        float4 p = *(const float4*)(base + (size_t)c * BIN);
        acc.x += p.x; acc.y += p.y; acc.z += p.z; acc.w += p.w;
    }
    float av[4] = {acc.x, acc.y, acc.z, acc.w};
#pragma unroll
    for (int k = 0; k < 4; ++k) {
        int i = i4 + k;
        float val = av[k] + ((i >= INPUT_SIZE) ? bias[i - INPUT_SIZE] : 0.0f);
        float nv  = (i < N_NEURONS - OUTPUT_SIZE) ? tanhf(val) : val;
        v[i] = nv;
        if (write_out && i >= N_NEURONS - OUTPUT_SIZE)
            out[i - (N_NEURONS - OUTPUT_SIZE)] = val;
    }
}

extern "C" void kernel_launch(void* const* d_in, const int* in_sizes, int n_in,
                              void* d_out, int out_size, void* d_ws, size_t ws_size,
                              hipStream_t stream) {
    const float* x    = (const float*)d_in[0];
    const float* w    = (const float*)d_in[1];
    const float* bias = (const float*)d_in[2];
    const int*   src  = (const int*)d_in[3];
    const int*   dst  = (const int*)d_in[4];
    float* out = (float*)d_out;

    const int blk = 256;
    const int grid_n   = (N_NEURONS + blk - 1) / blk;
    const int red_grid = (N_NEURONS / 4 + blk - 1) / blk;

    // ws layout: v | partials | p2 | hist | bases | gcur | recs
    float* v        = (float*)d_ws;
    float* partials = v + N_NEURONS;
    float* p2       = partials + (size_t)RANGES * CBLK * BIN;
    int*   hist     = (int*)(p2 + (size_t)RG * N_NEURONS);
    int*   bases    = hist + (size_t)RANGES * NCH;
    int*   gcur     = bases + (size_t)RANGES * NCH;
    int2*  recs     = (int2*)(gcur + RANGES);
    size_t need = (size_t)((char*)(recs + (size_t)RANGES * CAP) - (char*)d_ws);

    if (ws_size >= need) {
        hist_kernel<<<HIST_GRID, 256, 0, stream>>>(x, v, dst, hist);
        scan_kernel<<<RANGES, 1024, 0, stream>>>(hist, bases, gcur);
        partition_kernel<<<HIST_GRID, 256, 0, stream>>>(w, src, dst, bases, recs);
        for (int s = 0; s < STEPS; ++s) {
            scatter_sorted<<<RANGES * CBLK, SCAT_BLK, 0, stream>>>(
                recs, gcur, v, partials);
            reduce_stage1<<<dim3(red_grid, RG), blk, 0, stream>>>(partials, p2);
            reduce_stage2<<<red_grid, blk, 0, stream>>>(
                p2, bias, v, out, s == STEPS - 1 ? 1 : 0);
        }
    } else {
        long C = (long)(ws_size / 4 / N_NEURONS) - 1;
        if (C > 64) C = 64;
        if (C < 1) C = 1;
        float* part_fb = v + N_NEURONS;
        init_state_fb<<<grid_n, blk, 0, stream>>>(x, v);
        for (int s = 0; s < STEPS; ++s) {
            scatter_binned<<<RANGES * (int)C, SCAT_BLK, 0, stream>>>(
                w, src, dst, v, part_fb, (int)C);
            reduce_update_fb<<<red_grid, blk, 0, stream>>>(
                part_fb, bias, v, out, (int)C, s == STEPS - 1 ? 1 : 0);
        }
    }
}